// Round 20
// baseline (20.913 us; speedup 1.0000x reference)
//
#include <hip/hip_runtime.h>
#include <math.h>

// HungarianMatcher cost matrix:
//   C[i,j] = 5*L1(pred_box_i, tgt_box_j) + 2*focal(tgt class j) - 2*GIoU
// Shapes: pred_logits [BN,NC], pred_boxes [BN,4], tgt_ids [NT], tgt_bbox [NT,4]
// BN=16*900=14400, NC=91, NT=960. Output [BN,NT] fp32.
//
// R19: R18 (packed float2 rows, 20.9us) + __launch_bounds__(256,8).
// R16 showed the UNPACKED kernel can't fit 64 VGPR without spilling;
// R18's packing halves arithmetic registers (~50 live) so the 64-VGPR
// budget (8 waves/SIMD, the m69 occupancy cliff) is now reachable
// spill-free. This is the first variant that can test "latency-bound at
// 4 waves/SIMD" cleanly. Everything else identical to R18/R13.

#define ALPHA_F   0.25f
#define COST_CLS  2.0f
#define COST_BBOX 5.0f
#define COST_GIOU 2.0f
#define EPS_F     1e-8f

constexpr int THREADS = 256;

typedef float vfloat2 __attribute__((ext_vector_type(2)));

__device__ __forceinline__ vfloat2 sv(float v) { vfloat2 r; r.x = v; r.y = v; return r; }
__device__ __forceinline__ vfloat2 vmin2(vfloat2 a, vfloat2 b) {
    vfloat2 r; r.x = fminf(a.x, b.x); r.y = fminf(a.y, b.y); return r;
}
__device__ __forceinline__ vfloat2 vmax2(vfloat2 a, vfloat2 b) {
    vfloat2 r; r.x = fmaxf(a.x, b.x); r.y = fmaxf(a.y, b.y); return r;
}
__device__ __forceinline__ vfloat2 vabs2(vfloat2 a) {
    vfloat2 r; r.x = fabsf(a.x); r.y = fabsf(a.y); return r;
}

__device__ __forceinline__ float focal_entry(float x) {
    const float p  = 1.0f / (1.0f + __expf(-x));
    const float om = 1.0f - p;
    const float neg = (1.0f - ALPHA_F) * p * p * (-__logf(om + EPS_F));
    const float pos = ALPHA_F * om * om        * (-__logf(p  + EPS_F));
    return COST_CLS * (pos - neg) + COST_GIOU;   // GIoU "+2" folded in
}

// ---------------------- specialized kernel (ROWS = 2) -----------------------
template<int NC, int NT>
__global__ __launch_bounds__(THREADS, 8) void matcher_kernel_s(
    const float* __restrict__ logits,   // [BN, NC]
    const float* __restrict__ boxes,    // [BN, 4] cxcywh
    const int*   __restrict__ tids,     // [NT]
    const float* __restrict__ tboxes,   // [NT, 4] cxcywh
    float*       __restrict__ out)      // [BN, NT]
{
    constexpr int ROWS = 2;
    constexpr int JPT  = 4;                   // targets per thread (strided)
    constexpr int NJT  = NT / JPT;            // 240 active threads
    constexpr int NTAB = ROWS * NC;           // 182 table entries
    constexpr int CSTR = 2;                   // [class][row] pairs, b64-aligned

    __shared__ float s_cls[NC * CSTR];        // 728 B

    const int tid  = threadIdx.x;
    const int row0 = blockIdx.x * ROWS;
    const bool active = tid < NJT;

    // ---- issue the logit load first (head of the transcendental chain) ----
    float x = 0.0f;
    if (tid < NTAB)
        x = logits[(size_t)row0 * NC + tid];

    // ---- strided targets: ALL loads lane-coalesced ----
    float4 tb[JPT];
    int ic[JPT] = {0, 0, 0, 0};
    if (active) {
        #pragma unroll
        for (int k = 0; k < JPT; ++k) {
            tb[k] = reinterpret_cast<const float4*>(tboxes)[tid + k * NJT];
            ic[k] = tids[tid + k * NJT];
        }
    } else {
        #pragma unroll
        for (int k = 0; k < JPT; ++k) tb[k] = make_float4(0.f, 0.f, 0.f, 0.f);
    }

    // ---- focal class table: s_cls[c*2 + r], one chain per thread ----
    if (tid < NTAB) {
        const int r = (tid >= NC) ? 1 : 0;
        const int c = tid - (r ? NC : 0);
        s_cls[c * CSTR + r] = focal_entry(x);
    }
    __syncthreads();   // the only barrier

    if (!active) return;

    // ---- both rows' pred boxes packed into float2 per component ----
    const float4 pbA = reinterpret_cast<const float4*>(boxes)[row0];
    const float4 pbB = reinterpret_cast<const float4*>(boxes)[row0 + 1];
    vfloat2 pbx, pby, pbz, pbw;
    pbx.x = pbA.x; pbx.y = pbB.x;
    pby.x = pbA.y; pby.y = pbB.y;
    pbz.x = pbA.z; pbz.y = pbB.z;
    pbw.x = pbA.w; pbw.y = pbB.w;
    const vfloat2 px0 = pbx - 0.5f * pbz, py0 = pby - 0.5f * pbw;   // pk_fma
    const vfloat2 px1 = pbx + 0.5f * pbz, py1 = pby + 0.5f * pbw;
    const vfloat2 parea = pbz * pbw;

    float* __restrict__ obase = out + (size_t)row0 * NT + tid;
    #pragma unroll
    for (int k = 0; k < JPT; ++k) {
        const float4 t = tb[k];
        // target-derived (scalar, shared by both rows)
        const float hw = 0.5f * t.z, hh = 0.5f * t.w;
        const float tx0 = t.x - hw, tx1 = t.x + hw;
        const float ty0 = t.y - hh, ty1 = t.y + hh;
        const float tarea = t.z * t.w;
        // class pair: one aligned ds_read_b64
        const vfloat2 ctab = *reinterpret_cast<const vfloat2*>(&s_cls[ic[k] * CSTR]);
        // L1 (packed adds; abs via v_and per half)
        const vfloat2 l1 = (vabs2(pbx - sv(t.x)) + vabs2(pby - sv(t.y)))
                         + (vabs2(pbz - sv(t.z)) + vabs2(pbw - sv(t.w)));
        // raw intersection extents (packed subs, scalar min/max)
        const vfloat2 iwr = vmin2(px1, sv(tx1)) - vmax2(px0, sv(tx0));
        const vfloat2 ihr = vmin2(py1, sv(ty1)) - vmax2(py0, sv(ty0));
        const vfloat2 inter = vmax2(iwr, sv(0.0f)) * vmax2(ihr, sv(0.0f));
        const vfloat2 uni = (parea + sv(tarea)) - inter;
        // enclosing box via identity (packed)
        const vfloat2 cw = (pbz + sv(t.z)) - iwr;
        const vfloat2 ch = (pbw + sv(t.w)) - ihr;
        const vfloat2 carea = cw * ch;
        // C = 5*l1 + tbl - 2*(inter*carea + uni^2)/(uni*carea)
        const vfloat2 num = inter * carea + uni * uni;   // pk_mul + pk_fma
        const vfloat2 den = uni * carea;
        vfloat2 rcpd;
        rcpd.x = __builtin_amdgcn_rcpf(den.x);
        rcpd.y = __builtin_amdgcn_rcpf(den.y);
        const vfloat2 base = COST_BBOX * l1 + ctab;      // pk_fma
        const vfloat2 v = base - 2.0f * num * rcpd;      // pk_mul + pk_fma
        // coalesced NT dword stores (one per row)
        __builtin_nontemporal_store(v.x, obase + k * NJT);
        __builtin_nontemporal_store(v.y, obase + NT + k * NJT);
    }
}

// ----------------------------- generic fallback -----------------------------
constexpr int GROWS = 8;
__global__ __launch_bounds__(THREADS) void matcher_kernel_g(
    const float* __restrict__ logits, const float* __restrict__ boxes,
    const int* __restrict__ tids, const float* __restrict__ tboxes,
    float* __restrict__ out, int BN, int NC, int NT)
{
    extern __shared__ float s_cls_g[];
    const int tid  = threadIdx.x;
    const int row0 = blockIdx.x * GROWS;
    const int nrows = (BN - row0 < GROWS) ? (BN - row0) : GROWS;

    for (int t = tid; t < nrows * NC; t += THREADS) {
        const int r = t / NC, c = t - r * NC;
        const float x = logits[(size_t)(row0 + r) * NC + c];
        const float p  = 1.0f / (1.0f + expf(-x));
        const float om = 1.0f - p;
        const float neg = (1.0f - ALPHA_F) * p * p * (-logf(om + EPS_F));
        const float pos = ALPHA_F * om * om        * (-logf(p + EPS_F));
        s_cls_g[r * NC + c] = pos - neg;
    }
    __syncthreads();

    for (int r = 0; r < nrows; ++r) {
        const int row = row0 + r;
        const float4 pb = reinterpret_cast<const float4*>(boxes)[row];
        const float px0 = pb.x - 0.5f * pb.z, py0 = pb.y - 0.5f * pb.w;
        const float px1 = pb.x + 0.5f * pb.z, py1 = pb.y + 0.5f * pb.w;
        const float parea = pb.z * pb.w;
        for (int j = tid; j < NT; j += THREADS) {
            const float4 b = reinterpret_cast<const float4*>(tboxes)[j];
            const float bx0 = b.x - 0.5f * b.z, by0 = b.y - 0.5f * b.w;
            const float bx1 = b.x + 0.5f * b.z, by1 = b.y + 0.5f * b.w;
            const float l1 = fabsf(pb.x - b.x) + fabsf(pb.y - b.y)
                           + fabsf(pb.z - b.z) + fabsf(pb.w - b.w);
            const float iw = fmaxf(fminf(px1, bx1) - fmaxf(px0, bx0), 0.0f);
            const float ih = fmaxf(fminf(py1, by1) - fmaxf(py0, by0), 0.0f);
            const float inter = iw * ih;
            const float uni = parea + b.z * b.w - inter;
            const float iou = inter / uni;
            const float cw = fmaxf(px1, bx1) - fminf(px0, bx0);
            const float ch = fmaxf(py1, by1) - fminf(py0, by0);
            const float carea = cw * ch;
            const float giou = iou - (carea - uni) / carea;
            const float ccls = s_cls_g[r * NC + tids[j]];
            out[(size_t)row * NT + j] = COST_BBOX * l1 + COST_CLS * ccls - COST_GIOU * giou;
        }
        __syncthreads();
    }
}

extern "C" void kernel_launch(void* const* d_in, const int* in_sizes, int n_in,
                              void* d_out, int out_size, void* d_ws, size_t ws_size,
                              hipStream_t stream) {
    const float* logits = (const float*)d_in[0];
    const float* boxes  = (const float*)d_in[1];
    const int*   tids   = (const int*)d_in[2];
    const float* tboxes = (const float*)d_in[3];
    float* out = (float*)d_out;

    const int BN = in_sizes[1] / 4;       // 14400
    const int NC = in_sizes[0] / BN;      // 91
    const int NT = in_sizes[2];           // 960

    if (NC == 91 && NT == 960 && BN % 2 == 0) {
        matcher_kernel_s<91, 960><<<BN / 2, THREADS, 0, stream>>>(
            logits, boxes, tids, tboxes, out);
    } else {
        const int grid = (BN + GROWS - 1) / GROWS;
        const size_t shmem = (size_t)GROWS * NC * sizeof(float);
        matcher_kernel_g<<<grid, THREADS, shmem, stream>>>(
            logits, boxes, tids, tboxes, out, BN, NC, NT);
    }
}

// Round 21
// 19.712 us; speedup vs baseline: 1.0609x; 1.0609x over previous
//
#include <hip/hip_runtime.h>
#include <math.h>

// HungarianMatcher cost matrix:
//   C[i,j] = 5*L1(pred_box_i, tgt_box_j) + 2*focal(tgt class j) - 2*GIoU
// Shapes: pred_logits [BN,NC], pred_boxes [BN,4], tgt_ids [NT], tgt_bbox [NT,4]
// BN=16*900=14400, NC=91, NT=960. Output [BN,NT] fp32.
//
// R20: R13 (best, 20.8us) with 192-thread blocks: 960 = 192*5 -> JPT=5 and
// ALL threads active in the body (R13 wasted wave 3: full body issue for
// 48/64 lanes + 16 ballast lanes). 3 fully-utilized waves/block vs 4
// partially-utilized = -25% body issue. Focal entry via softplus identity:
// log(p)=x-sp(x), log(1-p)=-sp(x), sp(x)=log1p(exp(x)) -> 1 exp + 1 log
// instead of 1 exp + 2 logs (-33% trans). Else identical to R13: ROWS=2,
// grid 7200, strided coalesced loads, CSTR=3 table, NT dword stores.

#define ALPHA_F   0.25f
#define COST_CLS  2.0f
#define COST_BBOX 5.0f
#define COST_GIOU 2.0f
#define EPS_F     1e-8f

constexpr int THREADS = 192;          // 3 waves; 960 = 192*5

__device__ __forceinline__ float focal_entry(float x) {
    // p = sigmoid(x); sp = log(1+e^x) = softplus(x)
    // pos = A*(1-p)^2 * (sp - x)   [= -log(p)]
    // neg = (1-A)*p^2 * sp         [= -log(1-p)]
    // (EPS in the reference shifts log args by 1e-8; |delta| << 0.4 threshold)
    const float ex = __expf(x);
    const float p  = ex / (1.0f + ex);
    const float sp = __logf(1.0f + ex);
    const float om = 1.0f - p;
    const float pos = ALPHA_F * om * om * (sp - x);
    const float neg = (1.0f - ALPHA_F) * p * p * sp;
    return COST_CLS * (pos - neg) + COST_GIOU;   // GIoU "+2" folded in
}

// ---------------------- specialized kernel (ROWS = 2) -----------------------
template<int NC, int NT>
__global__ __launch_bounds__(THREADS) void matcher_kernel_s(
    const float* __restrict__ logits,   // [BN, NC]
    const float* __restrict__ boxes,    // [BN, 4] cxcywh
    const int*   __restrict__ tids,     // [NT]
    const float* __restrict__ tboxes,   // [NT, 4] cxcywh
    float*       __restrict__ out)      // [BN, NT]
{
    constexpr int ROWS = 2;
    constexpr int JPT  = NT / THREADS;        // 5 targets per thread (strided)
    constexpr int NTAB = ROWS * NC;           // 182 <= 192 threads
    constexpr int CSTR = 3;                   // class stride (coprime with 32)

    __shared__ float s_cls[NC * CSTR];        // ~1.1 KB

    const int tid  = threadIdx.x;
    const int row0 = blockIdx.x * ROWS;

    // ---- issue the logit load first (head of the transcendental chain) ----
    float x = 0.0f;
    if (tid < NTAB)
        x = logits[(size_t)row0 * NC + tid];

    // ---- strided targets: ALL loads lane-coalesced; all threads active ----
    float4 tb[JPT];
    int ic[JPT];
    #pragma unroll
    for (int k = 0; k < JPT; ++k) {
        tb[k] = reinterpret_cast<const float4*>(tboxes)[tid + k * THREADS];
        ic[k] = tids[tid + k * THREADS];
    }

    // ---- focal class table: s_cls[c*3 + r], one chain per thread ----
    if (tid < NTAB) {
        const int r = (tid >= NC) ? 1 : 0;
        const int c = tid - (r ? NC : 0);
        s_cls[c * CSTR + r] = focal_entry(x);
    }
    __syncthreads();   // the only barrier

    // ---- prefetch both rows' class costs to registers (ds_read) ----
    float cc0[JPT], cc1[JPT];
    #pragma unroll
    for (int k = 0; k < JPT; ++k) {
        const float* cp = s_cls + ic[k] * CSTR;
        cc0[k] = cp[0];
        cc1[k] = cp[1];
    }

    float* __restrict__ obase = out + (size_t)row0 * NT + tid;
    #pragma unroll
    for (int r = 0; r < ROWS; ++r) {
        // block-uniform pred box (scalar-load path)
        const float4 pb = reinterpret_cast<const float4*>(boxes)[row0 + r];
        const float px0 = pb.x - 0.5f * pb.z, py0 = pb.y - 0.5f * pb.w;
        const float px1 = pb.x + 0.5f * pb.z, py1 = pb.y + 0.5f * pb.w;
        const float parea = pb.z * pb.w;

        #pragma unroll
        for (int k = 0; k < JPT; ++k) {
            const float4 t = tb[k];
            const float hw = 0.5f * t.z, hh = 0.5f * t.w;
            const float tx0 = t.x - hw, tx1 = t.x + hw;
            const float ty0 = t.y - hh, ty1 = t.y + hh;
            const float tarea = t.z * t.w;
            // L1 in cxcywh space (abs folds into VOP3 src modifiers)
            const float l1 = (fabsf(pb.x - t.x) + fabsf(pb.y - t.y))
                           + (fabsf(pb.z - t.z) + fabsf(pb.w - t.w));
            // raw intersection extents (feed enclosing box too)
            const float iwr = fminf(px1, tx1) - fmaxf(px0, tx0);
            const float ihr = fminf(py1, ty1) - fmaxf(py0, ty0);
            const float inter = fmaxf(iwr, 0.0f) * fmaxf(ihr, 0.0f);
            const float uni = (parea + tarea) - inter;
            // enclosing box via identity: cw = pw + tw - iwr
            const float cw = (pb.z + t.z) - iwr;
            const float ch = (pb.w + t.w) - ihr;
            const float carea = cw * ch;
            // C = 5*l1 + tbl[c] - 2*(inter*carea + uni^2)/(uni*carea)
            const float num  = fmaf(inter, carea, uni * uni);
            const float rcpd = __builtin_amdgcn_rcpf(uni * carea);
            const float ctab = (r == 0) ? cc0[k] : cc1[k];
            const float base = fmaf(COST_BBOX, l1, ctab);
            const float v = fmaf(-2.0f * num, rcpd, base);
            // coalesced NT dword store: lane i -> out[... + i + k*192]
            __builtin_nontemporal_store(v, obase + (size_t)r * NT + k * THREADS);
        }
    }
}

// ----------------------------- generic fallback -----------------------------
constexpr int GTHREADS = 256;
constexpr int GROWS = 8;
__global__ __launch_bounds__(GTHREADS) void matcher_kernel_g(
    const float* __restrict__ logits, const float* __restrict__ boxes,
    const int* __restrict__ tids, const float* __restrict__ tboxes,
    float* __restrict__ out, int BN, int NC, int NT)
{
    extern __shared__ float s_cls_g[];
    const int tid  = threadIdx.x;
    const int row0 = blockIdx.x * GROWS;
    const int nrows = (BN - row0 < GROWS) ? (BN - row0) : GROWS;

    for (int t = tid; t < nrows * NC; t += GTHREADS) {
        const int r = t / NC, c = t - r * NC;
        const float x = logits[(size_t)(row0 + r) * NC + c];
        const float p  = 1.0f / (1.0f + expf(-x));
        const float om = 1.0f - p;
        const float neg = (1.0f - ALPHA_F) * p * p * (-logf(om + EPS_F));
        const float pos = ALPHA_F * om * om        * (-logf(p + EPS_F));
        s_cls_g[r * NC + c] = pos - neg;
    }
    __syncthreads();

    for (int r = 0; r < nrows; ++r) {
        const int row = row0 + r;
        const float4 pb = reinterpret_cast<const float4*>(boxes)[row];
        const float px0 = pb.x - 0.5f * pb.z, py0 = pb.y - 0.5f * pb.w;
        const float px1 = pb.x + 0.5f * pb.z, py1 = pb.y + 0.5f * pb.w;
        const float parea = pb.z * pb.w;
        for (int j = tid; j < NT; j += GTHREADS) {
            const float4 b = reinterpret_cast<const float4*>(tboxes)[j];
            const float bx0 = b.x - 0.5f * b.z, by0 = b.y - 0.5f * b.w;
            const float bx1 = b.x + 0.5f * b.z, by1 = b.y + 0.5f * b.w;
            const float l1 = fabsf(pb.x - b.x) + fabsf(pb.y - b.y)
                           + fabsf(pb.z - b.z) + fabsf(pb.w - b.w);
            const float iw = fmaxf(fminf(px1, bx1) - fmaxf(px0, bx0), 0.0f);
            const float ih = fmaxf(fminf(py1, by1) - fmaxf(py0, by0), 0.0f);
            const float inter = iw * ih;
            const float uni = parea + b.z * b.w - inter;
            const float iou = inter / uni;
            const float cw = fmaxf(px1, bx1) - fminf(px0, bx0);
            const float ch = fmaxf(py1, by1) - fminf(py0, by0);
            const float carea = cw * ch;
            const float giou = iou - (carea - uni) / carea;
            const float ccls = s_cls_g[r * NC + tids[j]];
            out[(size_t)row * NT + j] = COST_BBOX * l1 + COST_CLS * ccls - COST_GIOU * giou;
        }
        __syncthreads();
    }
}

extern "C" void kernel_launch(void* const* d_in, const int* in_sizes, int n_in,
                              void* d_out, int out_size, void* d_ws, size_t ws_size,
                              hipStream_t stream) {
    const float* logits = (const float*)d_in[0];
    const float* boxes  = (const float*)d_in[1];
    const int*   tids   = (const int*)d_in[2];
    const float* tboxes = (const float*)d_in[3];
    float* out = (float*)d_out;

    const int BN = in_sizes[1] / 4;       // 14400
    const int NC = in_sizes[0] / BN;      // 91
    const int NT = in_sizes[2];           // 960

    if (NC == 91 && NT == 960 && BN % 2 == 0) {
        matcher_kernel_s<91, 960><<<BN / 2, THREADS, 0, stream>>>(
            logits, boxes, tids, tboxes, out);
    } else {
        const int grid = (BN + GROWS - 1) / GROWS;
        const size_t shmem = (size_t)GROWS * NC * sizeof(float);
        matcher_kernel_g<<<grid, GTHREADS, shmem, stream>>>(
            logits, boxes, tids, tboxes, out, BN, NC, NT);
    }
}